// Round 1
// baseline (1583.767 us; speedup 1.0000x reference)
//
#include <hip/hip_runtime.h>

#define NB 512
#define T 128
#define NS 32
#define NC 16
#define NSC 48
#define PF 52   // pad stride for sF, sW, sQt (208 B rows, 16B-aligned)
#define PV 36   // pad stride for sV
#define PK 36   // pad stride for sKt / staged K rows

__device__ __forceinline__ float4 ld4(const float* p) { return *(const float4*)p; }
__device__ __forceinline__ void st4(float* p, float4 v) { *(float4*)p = v; }
__device__ __forceinline__ void fma4(float4& a, float s, float4 f) {
    a.x = fmaf(s, f.x, a.x); a.y = fmaf(s, f.y, a.y);
    a.z = fmaf(s, f.z, a.z); a.w = fmaf(s, f.w, a.w);
}
__device__ __forceinline__ float dot4(float4 a, float4 b) {
    return fmaf(a.x, b.x, fmaf(a.y, b.y, fmaf(a.z, b.z, a.w * b.w)));
}
// lane-constant broadcast via v_readlane_b32 (SGPR path, no LDS round trip)
__device__ __forceinline__ float rlane(float v, int l) {
    return __uint_as_float(__builtin_amdgcn_readlane(__float_as_uint(v), l));
}

// ================= backward Riccati kernel =================
// One block (256 threads) per batch element. 4 barriers per step.
// R1 changes: (a) Gauss-Jordan uses v_readlane + v_rcp_f32+NR instead of
// ds_bpermute shuffles + IEEE div; (b) wave rebalance: B-tiles moved off
// wave0 (tid>=160), K-writeout -> wave2, v -> wave3, so wave0 carries only
// A-tiles + GJ + D-tiles (max per-step wave load ~1580 -> ~1240 instr).
__global__ __launch_bounds__(256, 2)
void lqr_backward(const float* __restrict__ Q,
                  const float* __restrict__ p,
                  const float* __restrict__ A,
                  const float* __restrict__ Bm,
                  const float* __restrict__ c1,
                  float* __restrict__ Kws,
                  float* __restrict__ kws)
{
    const int b = blockIdx.x;
    const int tid = threadIdx.x;
    const int lane = tid & 63;
    const int wv = tid >> 6;

    __shared__ __align__(16) float sF[NS][PF];
    __shared__ __align__(16) float sW[NS][PF];
    __shared__ __align__(16) float sQt[NSC][PF];
    __shared__ __align__(16) float sV[NS][PV];
    __shared__ __align__(16) float sKt[NC][PK];
    __shared__ __align__(16) float sz[NS];
    __shared__ __align__(16) float sqt[NSC];
    __shared__ __align__(16) float sv[NS];
    __shared__ __align__(16) float sc1[NS];
    __shared__ __align__(16) float skt[NC];

    for (int e = tid; e < NS * NSC; e += 256) {
        int i = e / NSC, j = e % NSC;
        sF[i][j] = (j < NS) ? A[(size_t)b * NS * NS + i * NS + j]
                            : Bm[(size_t)b * NS * NC + i * NC + (j - NS)];
    }
    for (int e = tid; e < NS * NS; e += 256) sV[e >> 5][e & 31] = 0.f;
    if (tid < NS) { sv[tid] = 0.f; sc1[tid] = c1[(size_t)b * NS + tid]; }
    __syncthreads();

    for (int t = T - 1; t >= 0; --t) {
        const float* Qg = Q + ((size_t)b * T + t) * NSC * NSC;

        // ---- Phase A: W = V@F (tid 0..191, 2x4 tiles); z (tid 192..223);
        //      prefetch B-phase Q rows (tid 160..255) and p (tid 64..111) ----
        float4 qgb0 = {0,0,0,0}, qgb1 = {0,0,0,0};
        float preg = 0.f;
        if (tid >= 160) {
            int ct = tid - 160;
            int i0b = NS + (ct / 12) * 2, j0b = (ct % 12) * 4;
            qgb0 = ld4(Qg + i0b * NSC + j0b);
            qgb1 = ld4(Qg + (i0b + 1) * NSC + j0b);
        }
        if (tid >= 64 && tid < 112) preg = p[((size_t)b * T + t) * NSC + (tid - 64)];
        if (tid < 192) {
            const int i0 = (tid / 12) * 2, j0 = (tid % 12) * 4;
            float4 a0 = {0,0,0,0}, a1 = {0,0,0,0};
            #pragma unroll 8
            for (int k = 0; k < NS; ++k) {
                float2 v2 = *(const float2*)&sV[k][i0];   // V symmetric: V[i0..i0+1][k]
                float4 f4 = ld4(&sF[k][j0]);
                fma4(a0, v2.x, f4); fma4(a1, v2.y, f4);
            }
            st4(&sW[i0][j0], a0); st4(&sW[i0 + 1][j0], a1);
        } else if (tid < 224) {
            int i = tid - 192;
            float a = sv[i];
            #pragma unroll
            for (int k0 = 0; k0 < NS; k0 += 4)
                a += dot4(ld4(&sV[i][k0]), ld4(&sc1[k0]));
            sz[i] = a;
        }
        __syncthreads();

        // ---- Phase B: Qt rows 32..47 (Quu|Qux) (tid 160..255, 2x4 tiles);
        //      qt = p + F^T z (tid 64..111); prefetch C-phase Q (tid 64..191);
        //      wave0 idle (reserved for GJ) ----
        float4 qgc0 = {0,0,0,0}, qgc1 = {0,0,0,0};
        int i0c = 0, j0c = 0;
        if (tid >= 64 && tid < 192) {
            int ct = tid - 64; i0c = (ct / 8) * 2; j0c = (ct % 8) * 4;
            qgc0 = ld4(Qg + i0c * NSC + j0c);
            qgc1 = ld4(Qg + (i0c + 1) * NSC + j0c);
        }
        if (tid >= 160) {
            const int ct = tid - 160;
            const int i0b = NS + (ct / 12) * 2, j0b = (ct % 12) * 4;
            float4 a0 = qgb0, a1 = qgb1;
            #pragma unroll 8
            for (int k = 0; k < NS; ++k) {
                float2 f2 = *(const float2*)&sF[k][i0b];
                float4 w4 = ld4(&sW[k][j0b]);
                fma4(a0, f2.x, w4); fma4(a1, f2.y, w4);
            }
            st4(&sQt[i0b][j0b], a0); st4(&sQt[i0b + 1][j0b], a1);
        } else if (tid >= 64 && tid < 112) {
            int j = tid - 64;
            float a = preg;
            #pragma unroll 8
            for (int k = 0; k < NS; ++k) a = fmaf(sF[k][j], sz[k], a);
            sqt[j] = a;
        }
        __syncthreads();

        // ---- Phase C: wave0: in-register Gauss-Jordan (readlane + rcp+NR);
        //      tid 64..191: Qxx tiles ----
        if (wv == 0) {
            float R[NC];
            if (lane < NC) {
                #pragma unroll
                for (int i = 0; i < NC; ++i) R[i] = sQt[NS + i][NS + lane];
            } else if (lane < NSC) {
                #pragma unroll
                for (int i = 0; i < NC; ++i) R[i] = sQt[NS + i][lane - NC];
            } else if (lane == NSC) {
                #pragma unroll
                for (int i = 0; i < NC; ++i) R[i] = sqt[NS + i];
            } else {
                #pragma unroll
                for (int i = 0; i < NC; ++i) R[i] = 0.f;
            }
            #pragma unroll
            for (int k = 0; k < NC; ++k) {
                float pk = rlane(R[k], k);
                float inv = __builtin_amdgcn_rcpf(pk);
                inv = inv * fmaf(-pk, inv, 2.0f);      // 1 Newton step, ~0.5 ulp
                float tm = R[k] * inv;
                #pragma unroll
                for (int i = 0; i < NC; ++i) {
                    if (i == k) continue;
                    float cki = rlane(R[i], k);
                    R[i] = fmaf(-tm, cki, R[i]);
                }
                R[k] = tm;
            }
            if (lane >= NC && lane < NSC) {
                const int c = lane - NC;
                #pragma unroll
                for (int i = 0; i < NC; ++i) sKt[i][c] = -R[i];
            } else if (lane == NSC) {
                #pragma unroll
                for (int i = 0; i < NC; ++i) skt[i] = -R[i];
            }
        } else if (tid < 192) {
            float4 a0 = qgc0, a1 = qgc1;
            #pragma unroll 8
            for (int k = 0; k < NS; ++k) {
                float2 f2 = *(const float2*)&sF[k][i0c];
                float4 w4 = ld4(&sW[k][j0c]);
                fma4(a0, f2.x, w4); fma4(a1, f2.y, w4);
            }
            st4(&sQt[i0c][j0c], a0); st4(&sQt[i0c + 1][j0c], a1);
        }
        __syncthreads();

        // ---- Phase D: V = Qxx + Qxu@K (tid 0..127); K->ws (tid 128..159);
        //      v (tid 192..223); k->ws (tid 224..239) ----
        if (tid < 128) {
            const int i0 = (tid / 8) * 2, j0 = (tid % 8) * 4;
            float4 a0 = ld4(&sQt[i0][j0]), a1 = ld4(&sQt[i0 + 1][j0]);
            #pragma unroll
            for (int k = 0; k < NC; ++k) {
                float2 q2 = *(const float2*)&sQt[NS + k][i0];  // Qxu[i][k] = Qux[k][i]
                float4 k4 = ld4(&sKt[k][j0]);
                fma4(a0, q2.x, k4); fma4(a1, q2.y, k4);
            }
            st4(&sV[i0][j0], a0); st4(&sV[i0 + 1][j0], a1);
        } else if (tid < 160) {
            float4* Kg4 = (float4*)(Kws + ((size_t)b * T + t) * NC * NS);
            int e = (tid - 128) * 4;
            #pragma unroll
            for (int q = 0; q < 4; ++q)
                Kg4[e + q] = ld4(&sKt[(e + q) >> 3][((e + q) & 7) * 4]);
        } else if (tid >= 192 && tid < 224) {
            int j = tid - 192;
            float a = sqt[j];
            #pragma unroll
            for (int k = 0; k < NC; ++k) a = fmaf(sQt[NS + k][j], skt[k], a);
            sv[j] = a;
        } else if (tid >= 224 && tid < 240) {
            kws[((size_t)b * T + t) * NC + (tid - 224)] = skt[tid - 224];
        }
        __syncthreads();
    }
}

// ================= forward rollout kernel =================
// wave0: serial x/u chain (now via v_readlane broadcasts), 8-step chunks;
// waves1-3: stage next K chunk + consume previous chunk (cost, outputs).
__global__ __launch_bounds__(256, 2)
void lqr_forward(const float* __restrict__ x_init,
                 const float* __restrict__ Q,
                 const float* __restrict__ p,
                 const float* __restrict__ A,
                 const float* __restrict__ Bm,
                 const float* __restrict__ c1,
                 const float* __restrict__ Kws,
                 const float* __restrict__ kws,
                 float* __restrict__ out_x,
                 float* __restrict__ out_u,
                 float* __restrict__ out_cost)
{
    const int b = blockIdx.x;
    const int tid = threadIdx.x;
    const int lane = tid & 63;
    const int wv = tid >> 6;

    __shared__ __align__(16) float sK[2][8 * 576];   // [s][row][36] padded
    __shared__ __align__(16) float sk[2][128];       // [s][16]
    __shared__ __align__(16) float sxu[2][8][48];
    __shared__ float sred[4];

    float costAcc = 0.f;
    float4 Freg[12];
    float c1reg = 0.f, xu = 0.f;

    if (wv == 0) {
        const int i = lane & 31;               // all lanes load (avoid undef regs)
        const float* Ar = A + (size_t)b * NS * NS + i * NS;
        const float* Br = Bm + (size_t)b * NS * NC + i * NC;
        #pragma unroll
        for (int g = 0; g < 8; ++g) Freg[g] = ld4(Ar + g * 4);
        #pragma unroll
        for (int g = 0; g < 4; ++g) Freg[8 + g] = ld4(Br + g * 4);
        c1reg = c1[(size_t)b * NS + i];
        xu = x_init[(size_t)b * NS + i];
    } else {
        // preload K,k chunk 0 into buffer 0
        const float4* src = (const float4*)(Kws + (size_t)b * T * NC * NS);
        int ct = tid - 64;
        for (int idx = ct; idx < 1024; idx += 192) {
            int s = idx >> 7, rem = idx & 127, row = rem >> 3, jg = rem & 7;
            st4(&sK[0][s * 576 + row * 36 + jg * 4], src[idx]);
        }
        if (ct < 32) st4(&sk[0][ct * 4], ((const float4*)(kws + (size_t)b * T * NC))[ct]);
    }
    __syncthreads();

    for (int it = 0; it <= 16; ++it) {
        if (wv == 0) {
            if (it < 16) {
                const int buf = it & 1;
                for (int s = 0; s < 8; ++s) {
                    // K row for this lane (lanes 0..31 read redundantly - harmless)
                    const float* kb = &sK[buf][s * 576 + (lane & 15) * 36];
                    float4 Kq[8];
                    #pragma unroll
                    for (int g = 0; g < 8; ++g) Kq[g] = ld4(kb + g * 4);
                    float ktv = sk[buf][s * 16 + (lane & 15)];

                    float u0 = 0.f, u1 = 0.f;
                    #pragma unroll
                    for (int g = 0; g < 8; ++g) {
                        float x0 = rlane(xu, 4 * g + 0);
                        float x1 = rlane(xu, 4 * g + 1);
                        float x2 = rlane(xu, 4 * g + 2);
                        float x3 = rlane(xu, 4 * g + 3);
                        u0 = fmaf(Kq[g].x, x0, u0); u1 = fmaf(Kq[g].y, x1, u1);
                        u0 = fmaf(Kq[g].z, x2, u0); u1 = fmaf(Kq[g].w, x3, u1);
                    }
                    if (lane >= NS && lane < NSC) xu = u0 + u1 + ktv;
                    if (lane < NSC) sxu[buf][s][lane] = xu;

                    float a0 = 0.f, a1 = 0.f;
                    #pragma unroll
                    for (int g = 0; g < 12; ++g) {
                        float x0 = rlane(xu, 4 * g + 0);
                        float x1 = rlane(xu, 4 * g + 1);
                        float x2 = rlane(xu, 4 * g + 2);
                        float x3 = rlane(xu, 4 * g + 3);
                        a0 = fmaf(Freg[g].x, x0, a0); a1 = fmaf(Freg[g].y, x1, a1);
                        a0 = fmaf(Freg[g].z, x2, a0); a1 = fmaf(Freg[g].w, x3, a1);
                    }
                    if (lane < NS) xu = a0 + a1 + c1reg;
                }
            }
        } else {
            const int ct = tid - 64;
            if (it < 15) {   // stage K,k chunk it+1
                const int nbuf = (it + 1) & 1;
                const float4* src = (const float4*)(Kws + ((size_t)b * T + (it + 1) * 8) * NC * NS);
                for (int idx = ct; idx < 1024; idx += 192) {
                    int s = idx >> 7, rem = idx & 127, row = rem >> 3, jg = rem & 7;
                    st4(&sK[nbuf][s * 576 + row * 36 + jg * 4], src[idx]);
                }
                if (ct < 32) st4(&sk[nbuf][ct * 4],
                                 ((const float4*)(kws + ((size_t)b * T + (it + 1) * 8) * NC))[ct]);
            }
            if (it >= 1) {   // consume chunk it-1: cost + outputs
                const int buf = (it - 1) & 1;
                const int c = it - 1;
                for (int s = 0; s < 8; ++s) {
                    const int t = c * 8 + s;
                    const float* Qg = Q + ((size_t)b * T + t) * NSC * NSC;
                    #pragma unroll
                    for (int rr0 = 0; rr0 < 3; ++rr0) {
                        int rr = ct * 3 + rr0;
                        float4 q = ld4(Qg + rr * 4);
                        int i = rr / 12, j0 = (rr % 12) * 4;
                        float4 xv = ld4(&sxu[buf][s][j0]);
                        costAcc = fmaf(0.5f * sxu[buf][s][i], dot4(q, xv), costAcc);
                    }
                    if (ct < NSC) {
                        float xuv = sxu[buf][s][ct];
                        costAcc = fmaf(p[((size_t)b * T + t) * NSC + ct], xuv, costAcc);
                        if (ct < NS) out_x[((size_t)b * T + t) * NS + ct] = xuv;
                        else         out_u[((size_t)b * T + t) * NC + (ct - NS)] = xuv;
                    }
                }
            }
        }
        __syncthreads();
    }

    for (int off = 32; off > 0; off >>= 1)
        costAcc += __shfl_down(costAcc, off, 64);
    if ((tid & 63) == 0) sred[wv] = costAcc;
    __syncthreads();
    if (tid == 0) out_cost[b] = (sred[0] + sred[1]) + (sred[2] + sred[3]);
}

extern "C" void kernel_launch(void* const* d_in, const int* in_sizes, int n_in,
                              void* d_out, int out_size, void* d_ws, size_t ws_size,
                              hipStream_t stream) {
    const float* x_init = (const float*)d_in[0];
    const float* Q      = (const float*)d_in[1];
    const float* p      = (const float*)d_in[2];
    const float* A      = (const float*)d_in[3];
    const float* Bm     = (const float*)d_in[4];
    const float* c1     = (const float*)d_in[5];

    float* out      = (float*)d_out;
    float* out_x    = out;
    float* out_u    = out + (size_t)NB * T * NS;
    float* out_cost = out + (size_t)NB * T * (NS + NC);

    float* Kws = (float*)d_ws;
    float* kws = Kws + (size_t)NB * T * NC * NS;

    lqr_backward<<<NB, 256, 0, stream>>>(Q, p, A, Bm, c1, Kws, kws);
    lqr_forward<<<NB, 256, 0, stream>>>(x_init, Q, p, A, Bm, c1, Kws, kws,
                                        out_x, out_u, out_cost);
}